// Round 1
// baseline (216.571 us; speedup 1.0000x reference)
//
#include <hip/hip_runtime.h>

// Problem constants (fixed by setup_inputs): b=16, h=w=128, c=64, heads=4
#define B_   16
#define C_   64
#define HH   128
#define WW   128
#define NN   (HH*WW)      // 16384
#define NH   4
#define PADB 72           // bf16 row pad: 144B rows -> 16B aligned, 2-way-max banks
#define PADO 66           // f32 out-staging pad

typedef short short8 __attribute__((ext_vector_type(8)));
typedef float f32x4  __attribute__((ext_vector_type(4)));

// -log2(10000)/16
#define NEG_L2_10K_OVER16 (-0.8304820237218406f)

__device__ __forceinline__ float act_elu1(float v) {
    return v > 0.f ? v + 1.f : __expf(v);   // elu(v)+1
}
__device__ __forceinline__ short f2bf(float f) {
    union { float f; unsigned u; } v; v.f = f;
    unsigned r = (v.u + 0x7FFFu + ((v.u >> 16) & 1u)) >> 16;  // RNE
    return (short)r;
}
__device__ __forceinline__ float bf2f(short s) {
    union { unsigned u; float f; } v; v.u = ((unsigned)(unsigned short)s) << 16;
    return v.f;
}
// packed f32x2 -> bf16x2 (RNE), 1 instruction
__device__ __forceinline__ unsigned cvt2bf(float lo, float hi) {
    unsigned r;
    asm("v_cvt_pk_bf16_f32 %0, %1, %2" : "=v"(r) : "v"(lo), "v"(hi));
    return r;
}

// ---------------------------------------------------------------------------
// Init: rope table (cos,sin)[coord 0..127][theta 0..15], Wqk -> bf16,
// lepe weights transposed to [tap][ch].
// ---------------------------------------------------------------------------
__global__ __launch_bounds__(256) void la_init(
    const float* __restrict__ qk_w, const float* __restrict__ lepe_w,
    float2* __restrict__ g_tab, float* __restrict__ g_wT,
    short* __restrict__ g_wbf)
{
    int i = blockIdx.x * 256 + threadIdx.x;   // 0..8191
    g_wbf[i] = f2bf(qk_w[i]);
    if (i < 2048) {
        int coord = i >> 4, t = i & 15;
        float theta = exp2f(NEG_L2_10K_OVER16 * (float)t);
        float s, c;
        __sincosf((float)coord * theta, &s, &c);
        g_tab[i] = make_float2(c, s);
    }
    if (i < 576) {
        int tap = i >> 6, ch = i & 63;
        g_wT[i] = lepe_w[ch * 9 + tap];
    }
}

// ---------------------------------------------------------------------------
// Phase 1: k = elu(x@Wk^T+b)+1 (roped, -> kv/km partials) AND
//          q = elu(x@Wq^T+b)+1 (unroped, bf16 -> g_q for phase2).
// W fragments load straight from L2-resident g_wbf (no LDS staging).
// A fragments load straight from global x (L1-hot from the x^T staging pass).
// ---------------------------------------------------------------------------
__global__ __launch_bounds__(256) void la_phase1(
    const float* __restrict__ x, const float* __restrict__ qk_b,
    const short* __restrict__ g_wbf, const float2* __restrict__ g_tab,
    float* __restrict__ g_part, short* __restrict__ g_q)
{
    __shared__ __align__(16) char pool[3*64*PADB*2 + 256*4];   // 28672 B
    short* sXT = (short*)pool;                 // [64ch][72] x^T bf16
    short* sKT = sXT + 64*PADB;                // [64ch][72] roped-k^T bf16
    short* sQ  = sKT + 64*PADB;                // [64pos][72] q bf16 row-major
    float* kmp = (float*)(sQ + 64*PADB);       // [4][64]

    const int tid  = threadIdx.x;
    const int w    = tid >> 6;        // wave id = M-tile = head
    const int ln   = tid & 15;
    const int quad = (tid >> 4) & 3;
    const int b    = blockIdx.y;
    const int nblk = blockIdx.x;      // 0..63, 256 positions each
    const float* xb = x + (size_t)b * (size_t)(NN * C_);

    float biasK[4], biasQ[4];
    #pragma unroll
    for (int nt = 0; nt < 4; ++nt) {
        biasK[nt] = qk_b[64 + 16*nt + ln];
        biasQ[nt] = qk_b[16*nt + ln];
    }

    f32x4 acc2 = {0.f, 0.f, 0.f, 0.f};   // kv accumulator (head w)
    float kmacc[4] = {0.f, 0.f, 0.f, 0.f};

    for (int ck = 0; ck < 4; ++ck) {
        const int n0 = nblk*256 + ck*64;
        if (ck) __syncthreads();
        // stage x^T chunk (bf16)
        #pragma unroll
        for (int it = 0; it < 4; ++it) {
            int idx = tid + 256*it;
            int row = idx & 63, k4 = (idx >> 6) << 2;
            float4 xv = *(const float4*)(xb + (size_t)(n0 + row)*C_ + k4);
            unsigned p01 = cvt2bf(xv.x, xv.y), p23 = cvt2bf(xv.z, xv.w);
            sXT[(k4+0)*PADB + row] = (short)p01;
            sXT[(k4+1)*PADB + row] = (short)(p01 >> 16);
            sXT[(k4+2)*PADB + row] = (short)p23;
            sXT[(k4+3)*PADB + row] = (short)(p23 >> 16);
        }
        // A fragments direct from global x (f32 -> bf16)
        short8 aF[2];
        #pragma unroll
        for (int ks = 0; ks < 2; ++ks) {
            const float* ap = xb + (size_t)(n0 + 16*w + ln)*C_ + 32*ks + 8*quad;
            float4 a0 = *(const float4*)ap;
            float4 a1 = *(const float4*)(ap + 4);
            union { unsigned u[4]; short8 s; } af;
            af.u[0] = cvt2bf(a0.x, a0.y);
            af.u[1] = cvt2bf(a0.z, a0.w);
            af.u[2] = cvt2bf(a1.x, a1.y);
            af.u[3] = cvt2bf(a1.z, a1.w);
            aF[ks] = af.s;
        }
        // k and q tiles: M=64 pos, N=64 ch, K=64; no barrier needed (no LDS dep)
        f32x4 ak[4], aq[4];
        #pragma unroll
        for (int nt = 0; nt < 4; ++nt) { ak[nt] = (f32x4){0.f,0.f,0.f,0.f}; aq[nt] = (f32x4){0.f,0.f,0.f,0.f}; }
        #pragma unroll
        for (int ks = 0; ks < 2; ++ks) {
            #pragma unroll
            for (int nt = 0; nt < 4; ++nt) {
                short8 bk = *(const short8*)(g_wbf + (64 + 16*nt + ln)*C_ + 32*ks + 8*quad);
                short8 bq = *(const short8*)(g_wbf + (16*nt + ln)*C_ + 32*ks + 8*quad);
                ak[nt] = __builtin_amdgcn_mfma_f32_16x16x32_bf16(aF[ks], bk, ak[nt], 0, 0, 0);
                aq[nt] = __builtin_amdgcn_mfma_f32_16x16x32_bf16(aF[ks], bq, aq[nt], 0, 0, 0);
            }
        }
        // bias + elu; k: rope (table) -> sKT, km; q: -> sQ
        const int ycoord = n0 >> 7;        // constant within a 64-pos chunk
        const int x0 = n0 & 127;
        #pragma unroll
        for (int nt = 0; nt < 4; ++nt) {
            const int j = 16*nt + ln;          // channel (C/D col)
            const int t = j >> 1;              // rope pair index
            const float sgn = (j & 1) ? 1.f : -1.f;
            float2 cs_y;
            if (nt < 2) cs_y = g_tab[ycoord*16 + t];     // t<16: y-rope, chunk-const
            #pragma unroll
            for (int r = 0; r < 4; ++r) {
                int p_loc = 16*w + 4*quad + r;
                float kval = act_elu1(ak[nt][r] + biasK[nt]);
                kmacc[nt] += kval;
                float P = __shfl_xor(kval, 1);
                float2 cs = (nt < 2) ? cs_y : g_tab[(x0 + p_loc)*16 + (t - 16)];
                float kr = kval*cs.x + sgn*P*cs.y;
                sKT[j*PADB + p_loc] = f2bf(kr);
                float qval = act_elu1(aq[nt][r] + biasQ[nt]);
                sQ[p_loc*PADB + j] = f2bf(qval);
            }
        }
        __syncthreads();
        // kv += k_rope^T v : per head (= wave w), K=64 positions
        #pragma unroll
        for (int ks = 0; ks < 2; ++ks) {
            short8 a  = *(const short8*)(sKT + (16*w + ln)*PADB + 32*ks + 8*quad);
            short8 bf = *(const short8*)(sXT + (16*w + ln)*PADB + 32*ks + 8*quad);
            acc2 = __builtin_amdgcn_mfma_f32_16x16x32_bf16(a, bf, acc2, 0, 0, 0);
        }
        // q LDS -> global, fully coalesced 16B stores
        #pragma unroll
        for (int cp = 0; cp < 2; ++cp) {
            int idx = tid + 256*cp;           // 0..511
            int row = idx >> 3, c8 = idx & 7;
            short8 qv = *(const short8*)(sQ + row*PADB + 8*c8);
            *(short8*)(g_q + ((size_t)b*NN + n0 + row)*C_ + 8*c8) = qv;
        }
    }

    // store partials: [blk][1088] = 1024 kv + 64 km
    float* pb = g_part + (size_t)(b*64 + nblk) * 1088;
    #pragma unroll
    for (int r = 0; r < 4; ++r)
        pb[w*256 + (4*quad + r)*16 + ln] = acc2[r];

    #pragma unroll
    for (int nt = 0; nt < 4; ++nt) {
        float v = kmacc[nt];
        v += __shfl_xor(v, 16);
        v += __shfl_xor(v, 32);
        if ((tid & 63) < 16) kmp[w*64 + 16*nt + ln] = v;
    }
    __syncthreads();
    if (tid < 64)
        pb[1024 + tid] = kmp[tid] + kmp[64 + tid] + kmp[128 + tid] + kmp[192 + tid];
}

// ---------------------------------------------------------------------------
// Reduce: sum 64 per-block partials -> g_kv[b][1024], g_km[b][64]
// ---------------------------------------------------------------------------
__global__ __launch_bounds__(256) void la_reduce(
    const float* __restrict__ g_part, float* __restrict__ g_kv,
    float* __restrict__ g_km)
{
    int o = blockIdx.x * 256 + threadIdx.x;     // 0 .. 17407
    int b = o / 1088;
    int i = o - b * 1088;
    const float* p = g_part + (size_t)(b*64) * 1088 + i;
    float s = 0.f;
    #pragma unroll 8
    for (int nb = 0; nb < 64; ++nb) s += p[(size_t)nb * 1088];
    if (i < 1024) g_kv[b*1024 + i] = s;
    else          g_km[b*64 + (i - 1024)] = s;
}

// ---------------------------------------------------------------------------
// Phase 2: q-path entirely in registers (q bf16 from g_q; z folded into the
// A operand before MFMA), + vectorized lepe 3x3 depthwise conv.
// ---------------------------------------------------------------------------
__global__ __launch_bounds__(256) void la_phase2(
    const float* __restrict__ x, const short* __restrict__ g_q,
    const float* __restrict__ g_kv, const float* __restrict__ g_km,
    const float2* __restrict__ g_tab, const float* __restrict__ g_wT,
    const float* __restrict__ lepe_b, float* __restrict__ out)
{
    __shared__ __align__(16) char pool[64*40*2 + 64*PADO*4];   // 22016 B
    short* sKVB = (short*)pool;                    // [64][40] head-padded kv^T
    float* sOut = (float*)(pool + 64*40*2);        // [64ch][66] f32

    const int tid  = threadIdx.x;
    const int w    = tid >> 6;
    const int ln   = tid & 15;
    const int quad = (tid >> 4) & 3;
    const int b    = blockIdx.y;
    const int n0   = blockIdx.x * 64;
    const float* xb = x + (size_t)b * (size_t)(NN * C_);
    const float inv_n = 1.f / (float)NN;

    // kv (normalized) into B-operand layout, zero-padded to K=32 per head pair
    for (int idx = tid; idx < 1024; idx += 256) {
        int h = idx >> 8, d = (idx >> 4) & 15, e = idx & 15;
        float v = g_kv[b*1024 + idx] * inv_n;
        int rowb = h*16 + e;
        int kpos  = (h & 1) ? 16 + d : d;
        int kzero = (h & 1) ? d : 16 + d;
        sKVB[rowb*40 + kpos]  = f2bf(v);
        sKVB[rowb*40 + kzero] = 0;
    }

    // ---- q path: load bf16 q as A-fragment slices, rope+z in registers ----
    const int pos    = n0 + 16*w + ln;
    const int ycoord = n0 >> 7;
    const int xcoord = (n0 & 127) + 16*w + ln;
    const short* qp = g_q + ((size_t)b*NN + pos)*C_;
    short8 q0 = *(const short8*)(qp + 8*quad);        // ch 8q..8q+8   (heads 0/1)
    short8 q1 = *(const short8*)(qp + 32 + 8*quad);   // ch 32+8q..+8  (heads 2/3)
    float qa[8], qb[8];
    #pragma unroll
    for (int i = 0; i < 8; ++i) { qa[i] = bf2f(q0[i]); qb[i] = bf2f(q1[i]); }

    // z per (pos, head): this lane's 8-ch slice is exactly half of one head;
    // shfl_xor(16) pairs the quads of the same head.
    const float* kmb = g_km + b*64;
    f32x4 km0 = *(const f32x4*)(kmb + 8*quad);
    f32x4 km1 = *(const f32x4*)(kmb + 8*quad + 4);
    f32x4 km2 = *(const f32x4*)(kmb + 32 + 8*quad);
    f32x4 km3 = *(const f32x4*)(kmb + 32 + 8*quad + 4);
    float d0 = 0.f, d1 = 0.f;
    #pragma unroll
    for (int i = 0; i < 4; ++i) {
        d0 += qa[i]*km0[i] + qa[4+i]*km1[i];
        d1 += qb[i]*km2[i] + qb[4+i]*km3[i];
    }
    d0 += __shfl_xor(d0, 16);
    d1 += __shfl_xor(d1, 16);
    const float z0 = 1.f / (d0*inv_n + 1e-6f);
    const float z1 = 1.f / (d1*inv_n + 1e-6f);

    // rope (pairs are lane-local) + z-scale + pack; slice0 = y-rope, slice1 = x-rope
    const float* tyP = (const float*)g_tab + (ycoord*16 + 4*quad)*2;
    const float* txP = (const float*)g_tab + (xcoord*16 + 4*quad)*2;
    f32x4 ty0 = *(const f32x4*)tyP, ty1 = *(const f32x4*)(tyP + 4);
    f32x4 tx0 = *(const f32x4*)txP, tx1 = *(const f32x4*)(txP + 4);
    float cy[4] = {ty0[0], ty0[2], ty1[0], ty1[2]};
    float sy[4] = {ty0[1], ty0[3], ty1[1], ty1[3]};
    float cx[4] = {tx0[0], tx0[2], tx1[0], tx1[2]};
    float sx[4] = {tx0[1], tx0[3], tx1[1], tx1[3]};
    union { unsigned u[4]; short8 s; } A0, A1;
    #pragma unroll
    for (int p = 0; p < 4; ++p) {
        float e0 = qa[2*p], o0 = qa[2*p+1];
        A0.u[p] = cvt2bf((e0*cy[p] - o0*sy[p])*z0, (e0*sy[p] + o0*cy[p])*z0);
        float e1 = qb[2*p], o1 = qb[2*p+1];
        A1.u[p] = cvt2bf((e1*cx[p] - o1*sx[p])*z1, (e1*sx[p] + o1*cx[p])*z1);
    }

    __syncthreads();   // sKVB ready

    // out = (z*q_rope) @ kv_n : head-mismatched A elements hit B's zero pad
    f32x4 accq[4];
    #pragma unroll
    for (int h = 0; h < 4; ++h) accq[h] = (f32x4){0.f,0.f,0.f,0.f};
    #pragma unroll
    for (int hh = 0; hh < 2; ++hh) {
        short8 bf0 = *(const short8*)(sKVB + (hh*16 + ln)*40 + 8*quad);
        accq[hh]   = __builtin_amdgcn_mfma_f32_16x16x32_bf16(A0.s, bf0, accq[hh], 0, 0, 0);
        short8 bf1 = *(const short8*)(sKVB + ((2+hh)*16 + ln)*40 + 8*quad);
        accq[2+hh] = __builtin_amdgcn_mfma_f32_16x16x32_bf16(A1.s, bf1, accq[2+hh], 0, 0, 0);
    }
    #pragma unroll
    for (int h = 0; h < 4; ++h)
        #pragma unroll
        for (int r = 0; r < 4; ++r)
            sOut[(16*h + ln)*PADO + 16*w + 4*quad + r] = accq[h][r];

    // ---- lepe conv, vectorized: thread = (4 channels cg, 4 positions pg) ----
    const int cg = tid & 15;           // channels 4cg..4cg+4 (coalesced f32x4)
    const int pg = tid >> 4;
    const int p0 = 4*pg;
    const int yy = n0 >> 7, xbase = n0 & 127, gx0 = xbase + p0;
    f32x4 accl[4];
    #pragma unroll
    for (int j = 0; j < 4; ++j) accl[j] = (f32x4){0.f,0.f,0.f,0.f};
    #pragma unroll
    for (int dy = -1; dy <= 1; ++dy) {
        int y2 = yy + dy;
        if ((unsigned)y2 >= HH) continue;
        f32x4 wt0 = *(const f32x4*)(g_wT + ((dy+1)*3 + 0)*C_ + 4*cg);
        f32x4 wt1 = *(const f32x4*)(g_wT + ((dy+1)*3 + 1)*C_ + 4*cg);
        f32x4 wt2 = *(const f32x4*)(g_wT + ((dy+1)*3 + 2)*C_ + 4*cg);
        const float* rp = xb + (size_t)(y2*WW)*C_ + 4*cg;
        f32x4 cb[6];
        #pragma unroll
        for (int jj = 0; jj < 6; ++jj) {
            int col = gx0 - 1 + jj;
            cb[jj] = ((unsigned)col < WW) ? *(const f32x4*)(rp + (size_t)col*C_)
                                          : (f32x4){0.f,0.f,0.f,0.f};
        }
        #pragma unroll
        for (int j = 0; j < 4; ++j)
            accl[j] += cb[j]*wt0 + cb[j+1]*wt1 + cb[j+2]*wt2;
    }
    __syncthreads();   // attn results fully in sOut
    #pragma unroll
    for (int j = 0; j < 4; ++j)
        #pragma unroll
        for (int i = 0; i < 4; ++i)
            sOut[(4*cg + i)*PADO + p0 + j] += accl[j][i];
    __syncthreads();

    // bias + coalesced store (out is [b][c][n])
    const int ch = tid >> 2, sub = tid & 3, pp0 = 16*sub;
    const float lb = lepe_b[ch];
    float* outp = out + (size_t)b*(size_t)(C_*NN) + (size_t)ch*NN + n0 + pp0;
    #pragma unroll
    for (int g = 0; g < 4; ++g) {
        float2 a0 = *(const float2*)(sOut + ch*PADO + pp0 + 4*g);
        float2 a1 = *(const float2*)(sOut + ch*PADO + pp0 + 4*g + 2);
        float4 o4 = { a0.x + lb, a0.y + lb, a1.x + lb, a1.y + lb };
        *(float4*)(outp + 4*g) = o4;
    }
}

extern "C" void kernel_launch(void* const* d_in, const int* in_sizes, int n_in,
                              void* d_out, int out_size, void* d_ws, size_t ws_size,
                              hipStream_t stream) {
    const float* x      = (const float*)d_in[0];
    // d_in[1], d_in[2] are h, w (fixed 128x128 — hardcoded)
    const float* qk_w   = (const float*)d_in[3];
    const float* qk_b   = (const float*)d_in[4];
    const float* lepe_w = (const float*)d_in[5];
    const float* lepe_b = (const float*)d_in[6];
    float* out = (float*)d_out;

    // workspace layout (total ~38.1 MB)
    float*  g_part = (float*)d_ws;                 // 1024*1088 f  (4.46 MB)
    float*  g_kv   = g_part + 1024*1088;           // 16*1024 f
    float*  g_km   = g_kv + 16*1024;               // 16*64 f
    float2* g_tab  = (float2*)(g_km + 16*64);      // 2048 float2 (16 KB)
    float*  g_wT   = (float*)(g_tab + 2048);       // 576 f
    short*  g_wbf  = (short*)(g_wT + 576);         // 8192 shorts (16 KB)
    short*  g_q    = (short*)(g_wbf + 8192);       // 16*16384*64 shorts (32 MB)

    hipLaunchKernelGGL(la_init,   dim3(32),      dim3(256), 0, stream,
                       qk_w, lepe_w, g_tab, g_wT, g_wbf);
    hipLaunchKernelGGL(la_phase1, dim3(64, B_),  dim3(256), 0, stream,
                       x, qk_b, g_wbf, g_tab, g_part, g_q);
    hipLaunchKernelGGL(la_reduce, dim3(68),      dim3(256), 0, stream,
                       g_part, g_kv, g_km);
    hipLaunchKernelGGL(la_phase2, dim3(256, B_), dim3(256), 0, stream,
                       x, g_q, g_kv, g_km, g_tab, g_wT, lepe_b, out);
}

// Round 2
// 210.636 us; speedup vs baseline: 1.0282x; 1.0282x over previous
//
#include <hip/hip_runtime.h>

// Problem constants (fixed by setup_inputs): b=16, h=w=128, c=64, heads=4
#define B_   16
#define C_   64
#define HH   128
#define WW   128
#define NN   (HH*WW)      // 16384
#define PADB 72           // bf16 row pad: 144B rows -> 16B aligned, 2-way-max banks
#define PADO 66           // f32 out-staging pad

typedef short short8 __attribute__((ext_vector_type(8)));
typedef float f32x4  __attribute__((ext_vector_type(4)));

// -log2(10000)/16
#define NEG_L2_10K_OVER16 (-0.8304820237218406f)
#define INV2PI 0.15915494309189535f

__device__ __forceinline__ float act_elu1(float v) {
    return v > 0.f ? v + 1.f : __expf(v);   // elu(v)+1
}
__device__ __forceinline__ short f2bf(float f) {
    union { float f; unsigned u; } v; v.f = f;
    unsigned r = (v.u + 0x7FFFu + ((v.u >> 16) & 1u)) >> 16;  // RNE
    return (short)r;
}
// packed f32x2 -> bf16x2 (RNE), 1 instruction
__device__ __forceinline__ unsigned cvt2bf(float lo, float hi) {
    unsigned r;
    asm("v_cvt_pk_bf16_f32 %0, %1, %2" : "=v"(r) : "v"(lo), "v"(hi));
    return r;
}
// hardware sin/cos: input in revolutions (angle/2pi), rev >= 0
__device__ __forceinline__ void hw_sincos(float rev, float* s, float* c) {
    float f = rev - floorf(rev);
    *s = __builtin_amdgcn_sinf(f);
    *c = __builtin_amdgcn_cosf(f);
}

// ---------------------------------------------------------------------------
// Phase 1: k = elu(x@Wk^T+b)+1 (roped) -> kv = k_rope^T v and km = sum(k),
// accumulated with device-scope atomics into g_kv/g_km (zeroed by memset).
// W fragments hoisted to registers from f32 qk_w; A fragments direct from x.
// ---------------------------------------------------------------------------
__global__ __launch_bounds__(256) void la_phase1(
    const float* __restrict__ x, const float* __restrict__ qk_w,
    const float* __restrict__ qk_b, float* __restrict__ g_kv,
    float* __restrict__ g_km)
{
    __shared__ __align__(16) char pool[2*64*PADB*2 + 256*4];   // 19456 B
    short* sXT = (short*)pool;                 // [64ch][72] x^T bf16
    short* sKT = sXT + 64*PADB;                // [64ch][72] roped-k^T bf16
    float* kmp = (float*)(sKT + 64*PADB);      // [4][64]

    const int tid  = threadIdx.x;
    const int w    = tid >> 6;        // wave id = M-tile = head
    const int ln   = tid & 15;
    const int quad = (tid >> 4) & 3;
    const int b    = blockIdx.y;
    const int nblk = blockIdx.x;      // 0..127, 128 positions each
    const float* xb = x + (size_t)b * (size_t)(NN * C_);

    // hoist Wk fragments (f32 -> bf16): B[col=16nt+ln][k=32ks+8quad..+8]
    short8 bk[2][4];
    #pragma unroll
    for (int ks = 0; ks < 2; ++ks)
        #pragma unroll
        for (int nt = 0; nt < 4; ++nt) {
            const float* wp = qk_w + (64 + 16*nt + ln)*C_ + 32*ks + 8*quad;
            float4 w0 = *(const float4*)wp, w1 = *(const float4*)(wp + 4);
            union { unsigned u[4]; short8 s; } uf;
            uf.u[0] = cvt2bf(w0.x, w0.y); uf.u[1] = cvt2bf(w0.z, w0.w);
            uf.u[2] = cvt2bf(w1.x, w1.y); uf.u[3] = cvt2bf(w1.z, w1.w);
            bk[ks][nt] = uf.s;
        }
    float biasK[4];
    #pragma unroll
    for (int nt = 0; nt < 4; ++nt) biasK[nt] = qk_b[64 + 16*nt + ln];

    // per-lane rope thetas in revolution units; t = 8*(nt&1) + (ln>>1)
    float th[2];
    #pragma unroll
    for (int i = 0; i < 2; ++i)
        th[i] = exp2f(NEG_L2_10K_OVER16 * (float)(8*i + (ln >> 1))) * INV2PI;
    // y-rope: ycoord = nblk, constant for the whole block
    float sy[2], cy[2];
    #pragma unroll
    for (int i = 0; i < 2; ++i) hw_sincos((float)nblk * th[i], &sy[i], &cy[i]);

    f32x4 acc2 = {0.f, 0.f, 0.f, 0.f};   // kv accumulator (head w)
    float kmacc[4] = {0.f, 0.f, 0.f, 0.f};
    const int p_base = 16*w + 4*quad;

    for (int ck = 0; ck < 2; ++ck) {
        const int n0 = nblk*128 + ck*64;
        if (ck) __syncthreads();
        // stage x^T chunk (bf16)
        #pragma unroll
        for (int it = 0; it < 4; ++it) {
            int idx = tid + 256*it;
            int row = idx & 63, k4 = (idx >> 6) << 2;
            float4 xv = *(const float4*)(xb + (size_t)(n0 + row)*C_ + k4);
            unsigned p01 = cvt2bf(xv.x, xv.y), p23 = cvt2bf(xv.z, xv.w);
            sXT[(k4+0)*PADB + row] = (short)p01;
            sXT[(k4+1)*PADB + row] = (short)(p01 >> 16);
            sXT[(k4+2)*PADB + row] = (short)p23;
            sXT[(k4+3)*PADB + row] = (short)(p23 >> 16);
        }
        // A fragments direct from global x (f32 -> bf16)
        short8 aF[2];
        #pragma unroll
        for (int ks = 0; ks < 2; ++ks) {
            const float* ap = xb + (size_t)(n0 + 16*w + ln)*C_ + 32*ks + 8*quad;
            float4 a0 = *(const float4*)ap;
            float4 a1 = *(const float4*)(ap + 4);
            union { unsigned u[4]; short8 s; } af;
            af.u[0] = cvt2bf(a0.x, a0.y);
            af.u[1] = cvt2bf(a0.z, a0.w);
            af.u[2] = cvt2bf(a1.x, a1.y);
            af.u[3] = cvt2bf(a1.z, a1.w);
            aF[ks] = af.s;
        }
        // k-tile = X @ Wk^T : M=64 pos, N=64 ch, K=64
        f32x4 ak[4];
        #pragma unroll
        for (int nt = 0; nt < 4; ++nt) ak[nt] = (f32x4){0.f,0.f,0.f,0.f};
        #pragma unroll
        for (int ks = 0; ks < 2; ++ks)
            #pragma unroll
            for (int nt = 0; nt < 4; ++nt)
                ak[nt] = __builtin_amdgcn_mfma_f32_16x16x32_bf16(aF[ks], bk[ks][nt], ak[nt], 0, 0, 0);

        // bias + elu + rope (hw sincos) -> sKT; accumulate km
        const int x0 = ck*64;                      // n0 & 127
        #pragma unroll
        for (int nt = 0; nt < 4; ++nt) {
            const int j = 16*nt + ln;              // channel (C/D col)
            const float sgn = (j & 1) ? 1.f : -1.f;
            #pragma unroll
            for (int r = 0; r < 4; ++r) {
                int p_loc = p_base + r;
                float kval = act_elu1(ak[nt][r] + biasK[nt]);
                kmacc[nt] += kval;
                float P = __shfl_xor(kval, 1);
                float s, c;
                if (nt < 2) { s = sy[nt]; c = cy[nt]; }
                else hw_sincos((float)(x0 + p_loc) * th[nt & 1], &s, &c);
                sKT[j*PADB + p_loc] = f2bf(kval*c + sgn*P*s);
            }
        }
        __syncthreads();
        // kv += k_rope^T v : per head (= wave w), K=64 positions
        #pragma unroll
        for (int ks = 0; ks < 2; ++ks) {
            short8 a  = *(const short8*)(sKT + (16*w + ln)*PADB + 32*ks + 8*quad);
            short8 bf = *(const short8*)(sXT + (16*w + ln)*PADB + 32*ks + 8*quad);
            acc2 = __builtin_amdgcn_mfma_f32_16x16x32_bf16(a, bf, acc2, 0, 0, 0);
        }
    }

    // accumulate kv into g_kv[b][h*256 + d*16 + e] (device-scope atomics)
    float* kvb = g_kv + b*1024;
    #pragma unroll
    for (int r = 0; r < 4; ++r)
        atomicAdd(kvb + w*256 + (4*quad + r)*16 + ln, acc2[r]);

    // km: reduce quads within wave, then waves via LDS, then atomic
    #pragma unroll
    for (int nt = 0; nt < 4; ++nt) {
        float v = kmacc[nt];
        v += __shfl_xor(v, 16);
        v += __shfl_xor(v, 32);
        if ((tid & 63) < 16) kmp[w*64 + 16*nt + ln] = v;
    }
    __syncthreads();
    if (tid < 64)
        atomicAdd(g_km + b*64 + tid,
                  kmp[tid] + kmp[64 + tid] + kmp[128 + tid] + kmp[192 + tid]);
}

// ---------------------------------------------------------------------------
// Phase 2: recompute q = elu(x@Wq^T+b)+1 via MFMA (A from x, W from qk_w),
// z from km, rope via hw sincos, z folded into sQ; out = q_rope@kv_n + lepe.
// ---------------------------------------------------------------------------
__global__ __launch_bounds__(256) void la_phase2(
    const float* __restrict__ x, const float* __restrict__ qk_w,
    const float* __restrict__ qk_b, const float* __restrict__ lepe_w,
    const float* __restrict__ lepe_b, const float* __restrict__ g_kv,
    const float* __restrict__ g_km, float* __restrict__ out)
{
    __shared__ __align__(16) char pool[5120 + 9216 + 16896 + 2304]; // 33536 B
    short* sKVB = (short*)pool;                      // [64][40] head-padded kv^T
    short* sQ   = (short*)(pool + 5120);             // [64pos][72] roped,z-scaled q
    float* sOut = (float*)(pool + 5120 + 9216);      // [64ch][66] f32
    float* sWT  = (float*)(pool + 5120 + 9216 + 16896); // [9tap][64ch]

    const int tid  = threadIdx.x;
    const int w    = tid >> 6;
    const int ln   = tid & 15;
    const int quad = (tid >> 4) & 3;
    const int b    = blockIdx.y;
    const int n0   = blockIdx.x * 64;
    const float* xb = x + (size_t)b * (size_t)(NN * C_);
    const float inv_n = 1.f / (float)NN;

    // kv (normalized) into B-operand layout, zero-padded to K=32 per head pair
    for (int idx = tid; idx < 1024; idx += 256) {
        int h = idx >> 8, d = (idx >> 4) & 15, e = idx & 15;
        float v = g_kv[b*1024 + idx] * inv_n;
        int rowb = h*16 + e;
        int kpos  = (h & 1) ? 16 + d : d;
        int kzero = (h & 1) ? d : 16 + d;
        sKVB[rowb*40 + kpos]  = f2bf(v);
        sKVB[rowb*40 + kzero] = 0;
    }
    // lepe weights transposed into LDS: sWT[tap][ch]
    if (tid < 144) {
        float4 lw = *(const float4*)(lepe_w + tid*4);
        float lwv[4] = {lw.x, lw.y, lw.z, lw.w};
        #pragma unroll
        for (int i = 0; i < 4; ++i) {
            int e = tid*4 + i, ch = e / 9, tap = e - ch*9;
            sWT[tap*64 + ch] = lwv[i];
        }
    }

    // Wq fragments (f32 -> bf16), hoisted
    short8 wq[2][4];
    #pragma unroll
    for (int ks = 0; ks < 2; ++ks)
        #pragma unroll
        for (int nt = 0; nt < 4; ++nt) {
            const float* wp = qk_w + (16*nt + ln)*C_ + 32*ks + 8*quad;
            float4 w0 = *(const float4*)wp, w1 = *(const float4*)(wp + 4);
            union { unsigned u[4]; short8 s; } uf;
            uf.u[0] = cvt2bf(w0.x, w0.y); uf.u[1] = cvt2bf(w0.z, w0.w);
            uf.u[2] = cvt2bf(w1.x, w1.y); uf.u[3] = cvt2bf(w1.z, w1.w);
            wq[ks][nt] = uf.s;
        }
    float biasq[4], kmv[4];
    #pragma unroll
    for (int nt = 0; nt < 4; ++nt) {
        biasq[nt] = qk_b[16*nt + ln];
        kmv[nt]   = g_km[b*64 + 16*nt + ln];
    }
    // A fragments direct from global x
    short8 aF[2];
    #pragma unroll
    for (int ks = 0; ks < 2; ++ks) {
        const float* ap = xb + (size_t)(n0 + 16*w + ln)*C_ + 32*ks + 8*quad;
        float4 a0 = *(const float4*)ap;
        float4 a1 = *(const float4*)(ap + 4);
        union { unsigned u[4]; short8 s; } af;
        af.u[0] = cvt2bf(a0.x, a0.y);
        af.u[1] = cvt2bf(a0.z, a0.w);
        af.u[2] = cvt2bf(a1.x, a1.y);
        af.u[3] = cvt2bf(a1.z, a1.w);
        aF[ks] = af.s;
    }
    // q-tile = X @ Wq^T
    f32x4 aq[4];
    #pragma unroll
    for (int nt = 0; nt < 4; ++nt) aq[nt] = (f32x4){0.f,0.f,0.f,0.f};
    #pragma unroll
    for (int ks = 0; ks < 2; ++ks)
        #pragma unroll
        for (int nt = 0; nt < 4; ++nt)
            aq[nt] = __builtin_amdgcn_mfma_f32_16x16x32_bf16(aF[ks], wq[ks][nt], aq[nt], 0, 0, 0);

    // bias + elu, then z per position (16 shfls total)
    float qv[4][4], dot[4] = {0.f, 0.f, 0.f, 0.f};
    #pragma unroll
    for (int nt = 0; nt < 4; ++nt)
        #pragma unroll
        for (int r = 0; r < 4; ++r) {
            qv[nt][r] = act_elu1(aq[nt][r] + biasq[nt]);
            dot[r] += qv[nt][r] * kmv[nt];
        }
    float zr[4];
    #pragma unroll
    for (int r = 0; r < 4; ++r) {
        float d = dot[r];
        d += __shfl_xor(d, 1);
        d += __shfl_xor(d, 2);
        d += __shfl_xor(d, 4);
        d += __shfl_xor(d, 8);
        zr[r] = 1.f / (d * inv_n + 1e-6f);
    }

    // rope (hw sincos) + z-scale -> sQ
    float th[2];
    #pragma unroll
    for (int i = 0; i < 2; ++i)
        th[i] = exp2f(NEG_L2_10K_OVER16 * (float)(8*i + (ln >> 1))) * INV2PI;
    const int ycoord = n0 >> 7;
    const int x0 = n0 & 127;
    float sy[2], cy[2];
    #pragma unroll
    for (int i = 0; i < 2; ++i) hw_sincos((float)ycoord * th[i], &sy[i], &cy[i]);
    const int p_base = 16*w + 4*quad;
    #pragma unroll
    for (int nt = 0; nt < 4; ++nt) {
        const int j = 16*nt + ln;
        const float sgn = (j & 1) ? 1.f : -1.f;
        #pragma unroll
        for (int r = 0; r < 4; ++r) {
            int p_loc = p_base + r;
            float s, c;
            if (nt < 2) { s = sy[nt]; c = cy[nt]; }
            else hw_sincos((float)(x0 + p_loc) * th[nt & 1], &s, &c);
            float P = __shfl_xor(qv[nt][r], 1);
            float qr = (qv[nt][r]*c + sgn*P*s) * zr[r];
            sQ[p_loc*PADB + j] = f2bf(qr);
        }
    }
    __syncthreads();   // sQ, sKVB, sWT ready

    // out = (z*q_rope) @ kv_n : head-mismatched A elements hit B's zero pad
    f32x4 accq[4];
    #pragma unroll
    for (int h = 0; h < 4; ++h) accq[h] = (f32x4){0.f,0.f,0.f,0.f};
    #pragma unroll
    for (int P2 = 0; P2 < 2; ++P2) {
        short8 a = *(const short8*)(sQ + (16*w + ln)*PADB + 32*P2 + 8*quad);
        #pragma unroll
        for (int hh = 0; hh < 2; ++hh) {
            int h = 2*P2 + hh;
            short8 bf = *(const short8*)(sKVB + (h*16 + ln)*40 + 8*quad);
            accq[h] = __builtin_amdgcn_mfma_f32_16x16x32_bf16(a, bf, accq[h], 0, 0, 0);
        }
    }
    #pragma unroll
    for (int h = 0; h < 4; ++h)
        #pragma unroll
        for (int r = 0; r < 4; ++r)
            sOut[(16*h + ln)*PADO + 16*w + 4*quad + r] = accq[h][r];

    // ---- lepe conv, vectorized: thread = (4 channels cg, 4 positions pg) ----
    const int cg = tid & 15;
    const int pg = tid >> 4;
    const int p0 = 4*pg;
    const int yy = n0 >> 7, xbase = n0 & 127, gx0 = xbase + p0;
    f32x4 accl[4];
    #pragma unroll
    for (int j = 0; j < 4; ++j) accl[j] = (f32x4){0.f,0.f,0.f,0.f};
    #pragma unroll
    for (int dy = -1; dy <= 1; ++dy) {
        int y2 = yy + dy;
        if ((unsigned)y2 >= HH) continue;
        f32x4 wt0 = *(const f32x4*)(sWT + ((dy+1)*3 + 0)*C_ + 4*cg);
        f32x4 wt1 = *(const f32x4*)(sWT + ((dy+1)*3 + 1)*C_ + 4*cg);
        f32x4 wt2 = *(const f32x4*)(sWT + ((dy+1)*3 + 2)*C_ + 4*cg);
        const float* rp = xb + (size_t)(y2*WW)*C_ + 4*cg;
        f32x4 cb[6];
        #pragma unroll
        for (int jj = 0; jj < 6; ++jj) {
            int col = gx0 - 1 + jj;
            cb[jj] = ((unsigned)col < WW) ? *(const f32x4*)(rp + (size_t)col*C_)
                                          : (f32x4){0.f,0.f,0.f,0.f};
        }
        #pragma unroll
        for (int j = 0; j < 4; ++j)
            accl[j] += cb[j]*wt0 + cb[j+1]*wt1 + cb[j+2]*wt2;
    }
    __syncthreads();   // attn results fully in sOut
    #pragma unroll
    for (int j = 0; j < 4; ++j)
        #pragma unroll
        for (int i = 0; i < 4; ++i)
            sOut[(4*cg + i)*PADO + p0 + j] += accl[j][i];
    __syncthreads();

    // bias + coalesced store (out is [b][c][n])
    const int ch = tid >> 2, sub = tid & 3, pp0 = 16*sub;
    const float lb = lepe_b[ch];
    float* outp = out + (size_t)b*(size_t)(C_*NN) + (size_t)ch*NN + n0 + pp0;
    #pragma unroll
    for (int g = 0; g < 4; ++g) {
        float2 a0 = *(const float2*)(sOut + ch*PADO + pp0 + 4*g);
        float2 a1 = *(const float2*)(sOut + ch*PADO + pp0 + 4*g + 2);
        float4 o4 = { a0.x + lb, a0.y + lb, a1.x + lb, a1.y + lb };
        *(float4*)(outp + 4*g) = o4;
    }
}

extern "C" void kernel_launch(void* const* d_in, const int* in_sizes, int n_in,
                              void* d_out, int out_size, void* d_ws, size_t ws_size,
                              hipStream_t stream) {
    const float* x      = (const float*)d_in[0];
    // d_in[1], d_in[2] are h, w (fixed 128x128 — hardcoded)
    const float* qk_w   = (const float*)d_in[3];
    const float* qk_b   = (const float*)d_in[4];
    const float* lepe_w = (const float*)d_in[5];
    const float* lepe_b = (const float*)d_in[6];
    float* out = (float*)d_out;

    // workspace: only kv/km accumulators (68 KB), zeroed each launch
    float* g_kv = (float*)d_ws;              // 16*1024 f
    float* g_km = g_kv + 16*1024;            // 16*64 f
    hipMemsetAsync(d_ws, 0, (size_t)(16*1024 + 16*64) * sizeof(float), stream);

    hipLaunchKernelGGL(la_phase1, dim3(128, B_), dim3(256), 0, stream,
                       x, qk_w, qk_b, g_kv, g_km);
    hipLaunchKernelGGL(la_phase2, dim3(256, B_), dim3(256), 0, stream,
                       x, qk_w, qk_b, lepe_w, lepe_b, g_kv, g_km, out);
}

// Round 3
// 202.502 us; speedup vs baseline: 1.0695x; 1.0402x over previous
//
#include <hip/hip_runtime.h>

// Problem constants (fixed by setup_inputs): b=16, h=w=128, c=64, heads=4
#define B_   16
#define C_   64
#define HH   128
#define WW   128
#define NN   (HH*WW)      // 16384
#define PADB 72           // bf16 row pad: 144B rows -> 16B aligned
#define PADO 66           // f32 out-staging pad

typedef short short8 __attribute__((ext_vector_type(8)));
typedef float f32x4  __attribute__((ext_vector_type(4)));

// -log2(10000)/16
#define NEG_L2_10K_OVER16 (-0.8304820237218406f)

__device__ __forceinline__ float act_elu1(float v) {
    return v > 0.f ? v + 1.f : __expf(v);   // elu(v)+1
}
__device__ __forceinline__ short f2bf(float f) {
    union { float f; unsigned u; } v; v.f = f;
    unsigned r = (v.u + 0x7FFFu + ((v.u >> 16) & 1u)) >> 16;  // RNE
    return (short)r;
}
// packed f32x2 -> bf16x2 (RNE), 1 instruction
__device__ __forceinline__ unsigned cvt2bf(float lo, float hi) {
    unsigned r;
    asm("v_cvt_pk_bf16_f32 %0, %1, %2" : "=v"(r) : "v"(lo), "v"(hi));
    return r;
}

// ---------------------------------------------------------------------------
// Phase-1 helpers
// ---------------------------------------------------------------------------
__device__ __forceinline__ void p1_chunk(
    const float* __restrict__ xb, int n0, int xbase, const short8 bk[2][4],
    const float* biasK, const float* sy, const float* cy, const float* th,
    int w, int ln, int quad, short* sKTb, float* kmacc)
{
    // A fragments direct from global x (L1-hot from the staging pass)
    short8 aF[2];
    #pragma unroll
    for (int ks = 0; ks < 2; ++ks) {
        const float* ap = xb + (size_t)(n0 + 16*w + ln)*C_ + 32*ks + 8*quad;
        float4 a0 = *(const float4*)ap, a1 = *(const float4*)(ap + 4);
        union { unsigned u[4]; short8 s; } af;
        af.u[0] = cvt2bf(a0.x, a0.y); af.u[1] = cvt2bf(a0.z, a0.w);
        af.u[2] = cvt2bf(a1.x, a1.y); af.u[3] = cvt2bf(a1.z, a1.w);
        aF[ks] = af.s;
    }
    // k-tile = X @ Wk^T : M=64 pos, N=64 ch, K=64
    f32x4 ak[4];
    #pragma unroll
    for (int nt = 0; nt < 4; ++nt) ak[nt] = (f32x4){0.f,0.f,0.f,0.f};
    #pragma unroll
    for (int ks = 0; ks < 2; ++ks)
        #pragma unroll
        for (int nt = 0; nt < 4; ++nt)
            ak[nt] = __builtin_amdgcn_mfma_f32_16x16x32_bf16(aF[ks], bk[ks][nt], ak[nt], 0, 0, 0);
    // bias + elu + rope -> sKTb (transposed); accumulate km
    const int p_base = 16*w + 4*quad;
    #pragma unroll
    for (int nt = 0; nt < 4; ++nt) {
        const int j = 16*nt + ln;              // channel (C/D col)
        const float sgn = (j & 1) ? 1.f : -1.f;
        #pragma unroll
        for (int r = 0; r < 4; ++r) {
            int p_loc = p_base + r;
            float kval = act_elu1(ak[nt][r] + biasK[nt]);
            kmacc[nt] += kval;
            float P = __shfl_xor(kval, 1);
            float s, c;
            if (nt < 2) { s = sy[nt]; c = cy[nt]; }
            else __sincosf((float)(xbase + p_loc) * th[nt & 1], &s, &c);
            sKTb[j*PADB + p_loc] = f2bf(kval*c + sgn*P*s);
        }
    }
}

__device__ __forceinline__ void p1_kv(
    const short* sKTb, const short* sXTb, int w, int ln, int quad, f32x4* acc2)
{
    #pragma unroll
    for (int ks = 0; ks < 2; ++ks) {
        short8 a  = *(const short8*)(sKTb + (16*w + ln)*PADB + 32*ks + 8*quad);
        short8 bf = *(const short8*)(sXTb + (16*w + ln)*PADB + 32*ks + 8*quad);
        *acc2 = __builtin_amdgcn_mfma_f32_16x16x32_bf16(a, bf, *acc2, 0, 0, 0);
    }
}

// ---------------------------------------------------------------------------
// Phase 1: k = elu(x@Wk^T+b)+1 (roped) -> kv = k_rope^T v and km = sum(k),
// accumulated with device-scope atomics. Software-pipelined over 2 chunks:
// chunk1's global loads are issued before chunk0's first barrier.
// ---------------------------------------------------------------------------
__global__ __launch_bounds__(256, 4) void la_phase1(
    const float* __restrict__ x, const float* __restrict__ qk_w,
    const float* __restrict__ qk_b, float* __restrict__ g_kv,
    float* __restrict__ g_km)
{
    __shared__ __align__(16) char pool[4*64*PADB*2 + 256*4];   // 37888 B
    short* sXT0 = (short*)pool;                // [64ch][72] x^T chunk0
    short* sKT0 = sXT0 + 64*PADB;              // [64ch][72] roped-k^T chunk0
    short* sXT1 = sKT0 + 64*PADB;              // chunk1
    short* sKT1 = sXT1 + 64*PADB;
    float* kmp  = (float*)(sKT1 + 64*PADB);    // [4][64]

    const int tid  = threadIdx.x;
    const int w    = tid >> 6;        // wave id = M-tile
    const int ln   = tid & 15;
    const int quad = (tid >> 4) & 3;
    const int b    = blockIdx.y;
    const int bx   = blockIdx.x;
    const int nblk = ((bx & 7) << 4) | (bx >> 3);   // XCD swizzle (128 = 8*16)
    const float* xb = x + (size_t)b * (size_t)(NN * C_);

    // hoist Wk fragments (f32 -> bf16)
    short8 bk[2][4];
    #pragma unroll
    for (int ks = 0; ks < 2; ++ks)
        #pragma unroll
        for (int nt = 0; nt < 4; ++nt) {
            const float* wp = qk_w + (64 + 16*nt + ln)*C_ + 32*ks + 8*quad;
            float4 w0 = *(const float4*)wp, w1 = *(const float4*)(wp + 4);
            union { unsigned u[4]; short8 s; } uf;
            uf.u[0] = cvt2bf(w0.x, w0.y); uf.u[1] = cvt2bf(w0.z, w0.w);
            uf.u[2] = cvt2bf(w1.x, w1.y); uf.u[3] = cvt2bf(w1.z, w1.w);
            bk[ks][nt] = uf.s;
        }
    float biasK[4];
    #pragma unroll
    for (int nt = 0; nt < 4; ++nt) biasK[nt] = qk_b[64 + 16*nt + ln];

    // rope thetas (radians); y-rope is block-constant (nblk is the image row)
    float th[2];
    #pragma unroll
    for (int i = 0; i < 2; ++i)
        th[i] = exp2f(NEG_L2_10K_OVER16 * (float)(8*i + (ln >> 1)));
    float sy[2], cy[2];
    #pragma unroll
    for (int i = 0; i < 2; ++i) __sincosf((float)nblk * th[i], &sy[i], &cy[i]);

    // ---- stage chunk0; issue chunk1 loads early ----
    const int srow = tid & 63, scol = (tid >> 6) << 2;   // cols scol + 16*it
    float4 xv0[4], xv1[4];
    #pragma unroll
    for (int it = 0; it < 4; ++it)
        xv0[it] = *(const float4*)(xb + (size_t)(nblk*128 + srow)*C_ + scol + 16*it);
    #pragma unroll
    for (int it = 0; it < 4; ++it) {
        int k4 = scol + 16*it;
        unsigned p01 = cvt2bf(xv0[it].x, xv0[it].y), p23 = cvt2bf(xv0[it].z, xv0[it].w);
        sXT0[(k4+0)*PADB + srow] = (short)p01;
        sXT0[(k4+1)*PADB + srow] = (short)(p01 >> 16);
        sXT0[(k4+2)*PADB + srow] = (short)p23;
        sXT0[(k4+3)*PADB + srow] = (short)(p23 >> 16);
    }
    #pragma unroll
    for (int it = 0; it < 4; ++it)
        xv1[it] = *(const float4*)(xb + (size_t)(nblk*128 + 64 + srow)*C_ + scol + 16*it);
    __syncthreads();                               // B1: sXT0 ready

    f32x4 acc2 = {0.f, 0.f, 0.f, 0.f};
    float kmacc[4] = {0.f, 0.f, 0.f, 0.f};

    p1_chunk(xb, nblk*128, 0, bk, biasK, sy, cy, th, w, ln, quad, sKT0, kmacc);
    // stage chunk1 (hidden under chunk0 compute)
    #pragma unroll
    for (int it = 0; it < 4; ++it) {
        int k4 = scol + 16*it;
        unsigned p01 = cvt2bf(xv1[it].x, xv1[it].y), p23 = cvt2bf(xv1[it].z, xv1[it].w);
        sXT1[(k4+0)*PADB + srow] = (short)p01;
        sXT1[(k4+1)*PADB + srow] = (short)(p01 >> 16);
        sXT1[(k4+2)*PADB + srow] = (short)p23;
        sXT1[(k4+3)*PADB + srow] = (short)(p23 >> 16);
    }
    __syncthreads();                               // B2: sKT0 + sXT1 ready
    p1_kv(sKT0, sXT0, w, ln, quad, &acc2);
    p1_chunk(xb, nblk*128 + 64, 64, bk, biasK, sy, cy, th, w, ln, quad, sKT1, kmacc);
    __syncthreads();                               // B3: sKT1 ready
    p1_kv(sKT1, sXT1, w, ln, quad, &acc2);

    // kv accumulate (device-scope atomics, 1024 distinct addrs per block)
    float* kvb = g_kv + b*1024;
    #pragma unroll
    for (int r = 0; r < 4; ++r)
        atomicAdd(kvb + w*256 + (4*quad + r)*16 + ln, acc2[r]);

    // km: quads within wave -> waves via LDS -> atomic
    #pragma unroll
    for (int nt = 0; nt < 4; ++nt) {
        float v = kmacc[nt];
        v += __shfl_xor(v, 16);
        v += __shfl_xor(v, 32);
        if ((tid & 63) < 16) kmp[w*64 + 16*nt + ln] = v;
    }
    __syncthreads();
    if (tid < 64)
        atomicAdd(g_km + b*64 + tid,
                  kmp[tid] + kmp[64 + tid] + kmp[128 + tid] + kmp[192 + tid]);
}

// ---------------------------------------------------------------------------
// Phase 2: recompute q = elu(x@Wq^T+b)+1 via MFMA, per-head z folded into q,
// rope, out = q_rope@kv_n + lepe. sOut aliases sKVB+sQ -> 19.2 KB LDS,
// 8 blocks/CU.
// ---------------------------------------------------------------------------
__global__ __launch_bounds__(256, 8) void la_phase2(
    const float* __restrict__ x, const float* __restrict__ qk_w,
    const float* __restrict__ qk_b, const float* __restrict__ lepe_w,
    const float* __restrict__ lepe_b, const float* __restrict__ g_kv,
    const float* __restrict__ g_km, float* __restrict__ out)
{
    __shared__ __align__(16) char pool[16896 + 2304];    // 19200 B
    short* sKVB = (short*)pool;                  // [64][40] head-padded kv^T
    short* sQ   = (short*)(pool + 5120);         // [64pos][72] roped,z-scaled q
    float* sOut = (float*)pool;                  // [64ch][66] — ALIASES sKVB+sQ
    float* sWT  = (float*)(pool + 16896);        // [9tap][64ch]

    const int tid  = threadIdx.x;
    const int w    = tid >> 6;
    const int ln   = tid & 15;
    const int quad = (tid >> 4) & 3;
    const int b    = blockIdx.y;
    const int bx   = blockIdx.x;
    const int n0   = (((bx & 7) << 5) | (bx >> 3)) * 64;   // XCD swizzle (256 = 8*32)
    const float* xb = x + (size_t)b * (size_t)(NN * C_);
    const float inv_n = 1.f / (float)NN;

    // kv (normalized) into B-operand layout, zero-padded to K=32 per head pair
    for (int idx = tid; idx < 1024; idx += 256) {
        int h = idx >> 8, d = (idx >> 4) & 15, e = idx & 15;
        float v = g_kv[b*1024 + idx] * inv_n;
        int rowb = h*16 + e;
        int kpos  = (h & 1) ? 16 + d : d;
        int kzero = (h & 1) ? d : 16 + d;
        sKVB[rowb*40 + kpos]  = f2bf(v);
        sKVB[rowb*40 + kzero] = 0;
    }
    // lepe weights transposed into LDS: sWT[tap][ch]
    if (tid < 144) {
        float4 lw = *(const float4*)(lepe_w + tid*4);
        float lwv[4] = {lw.x, lw.y, lw.z, lw.w};
        #pragma unroll
        for (int i = 0; i < 4; ++i) {
            int e = tid*4 + i, ch = e / 9, tap = e - ch*9;
            sWT[tap*64 + ch] = lwv[i];
        }
    }

    // Wq fragments (f32 -> bf16), hoisted
    short8 wq[2][4];
    #pragma unroll
    for (int ks = 0; ks < 2; ++ks)
        #pragma unroll
        for (int nt = 0; nt < 4; ++nt) {
            const float* wp = qk_w + (16*nt + ln)*C_ + 32*ks + 8*quad;
            float4 w0 = *(const float4*)wp, w1 = *(const float4*)(wp + 4);
            union { unsigned u[4]; short8 s; } uf;
            uf.u[0] = cvt2bf(w0.x, w0.y); uf.u[1] = cvt2bf(w0.z, w0.w);
            uf.u[2] = cvt2bf(w1.x, w1.y); uf.u[3] = cvt2bf(w1.z, w1.w);
            wq[ks][nt] = uf.s;
        }
    float biasq[4], kmv[4];
    #pragma unroll
    for (int nt = 0; nt < 4; ++nt) {
        biasq[nt] = qk_b[16*nt + ln];
        kmv[nt]   = g_km[b*64 + 16*nt + ln];
    }
    // A fragments direct from global x
    short8 aF[2];
    #pragma unroll
    for (int ks = 0; ks < 2; ++ks) {
        const float* ap = xb + (size_t)(n0 + 16*w + ln)*C_ + 32*ks + 8*quad;
        float4 a0 = *(const float4*)ap, a1 = *(const float4*)(ap + 4);
        union { unsigned u[4]; short8 s; } af;
        af.u[0] = cvt2bf(a0.x, a0.y);
        af.u[1] = cvt2bf(a0.z, a0.w);
        af.u[2] = cvt2bf(a1.x, a1.y);
        af.u[3] = cvt2bf(a1.z, a1.w);
        aF[ks] = af.s;
    }
    // q-tile = X @ Wq^T
    f32x4 aq[4];
    #pragma unroll
    for (int nt = 0; nt < 4; ++nt) aq[nt] = (f32x4){0.f,0.f,0.f,0.f};
    #pragma unroll
    for (int ks = 0; ks < 2; ++ks)
        #pragma unroll
        for (int nt = 0; nt < 4; ++nt)
            aq[nt] = __builtin_amdgcn_mfma_f32_16x16x32_bf16(aF[ks], wq[ks][nt], aq[nt], 0, 0, 0);

    // bias + elu + PER-HEAD z (head = nt: channels 16nt..16nt+15), folded into qv.
    // z is uniform over the 16 ln-lanes, so the shfl-pair partner has the same z.
    float qv[4][4];
    #pragma unroll
    for (int nt = 0; nt < 4; ++nt)
        #pragma unroll
        for (int r = 0; r < 4; ++r) {
            float q0 = act_elu1(aq[nt][r] + biasq[nt]);
            float dp = q0 * kmv[nt];
            dp += __shfl_xor(dp, 1);
            dp += __shfl_xor(dp, 2);
            dp += __shfl_xor(dp, 4);
            dp += __shfl_xor(dp, 8);
            qv[nt][r] = q0 / (dp * inv_n + 1e-6f);
        }

    // rope -> sQ (z already folded)
    float th[2];
    #pragma unroll
    for (int i = 0; i < 2; ++i)
        th[i] = exp2f(NEG_L2_10K_OVER16 * (float)(8*i + (ln >> 1)));
    const int ycoord = n0 >> 7;
    const int x0 = n0 & 127;
    float sy[2], cy[2];
    #pragma unroll
    for (int i = 0; i < 2; ++i) __sincosf((float)ycoord * th[i], &sy[i], &cy[i]);
    const int p_base = 16*w + 4*quad;
    #pragma unroll
    for (int nt = 0; nt < 4; ++nt) {
        const int j = 16*nt + ln;
        const float sgn = (j & 1) ? 1.f : -1.f;
        #pragma unroll
        for (int r = 0; r < 4; ++r) {
            int p_loc = p_base + r;
            float s, c;
            if (nt < 2) { s = sy[nt]; c = cy[nt]; }
            else __sincosf((float)(x0 + p_loc) * th[nt & 1], &s, &c);
            float P = __shfl_xor(qv[nt][r], 1);
            sQ[p_loc*PADB + j] = f2bf(qv[nt][r]*c + sgn*P*s);
        }
    }
    __syncthreads();   // B1: sQ, sKVB, sWT ready

    // out = (z*q_rope) @ kv_n : head-mismatched A elements hit B's zero pad
    f32x4 accq[4];
    #pragma unroll
    for (int h = 0; h < 4; ++h) accq[h] = (f32x4){0.f,0.f,0.f,0.f};
    #pragma unroll
    for (int P2 = 0; P2 < 2; ++P2) {
        short8 a = *(const short8*)(sQ + (16*w + ln)*PADB + 32*P2 + 8*quad);
        #pragma unroll
        for (int hh = 0; hh < 2; ++hh) {
            int h = 2*P2 + hh;
            short8 bf = *(const short8*)(sKVB + (h*16 + ln)*40 + 8*quad);
            accq[h] = __builtin_amdgcn_mfma_f32_16x16x32_bf16(a, bf, accq[h], 0, 0, 0);
        }
    }
    __syncthreads();   // B2: all reads of sKVB/sQ done — sOut may alias now

    #pragma unroll
    for (int h = 0; h < 4; ++h)
        #pragma unroll
        for (int r = 0; r < 4; ++r)
            sOut[(16*h + ln)*PADO + 16*w + 4*quad + r] = accq[h][r];

    // ---- lepe conv, vectorized: thread = (4 channels cg, 4 positions pg) ----
    const int cg = tid & 15;
    const int pg = tid >> 4;
    const int p0 = 4*pg;
    const int yy = n0 >> 7, xbase = n0 & 127, gx0 = xbase + p0;
    f32x4 accl[4];
    #pragma unroll
    for (int j = 0; j < 4; ++j) accl[j] = (f32x4){0.f,0.f,0.f,0.f};
    #pragma unroll
    for (int dy = -1; dy <= 1; ++dy) {
        int y2 = yy + dy;
        if ((unsigned)y2 >= HH) continue;
        f32x4 wt0 = *(const f32x4*)(sWT + ((dy+1)*3 + 0)*C_ + 4*cg);
        f32x4 wt1 = *(const f32x4*)(sWT + ((dy+1)*3 + 1)*C_ + 4*cg);
        f32x4 wt2 = *(const f32x4*)(sWT + ((dy+1)*3 + 2)*C_ + 4*cg);
        const float* rp = xb + (size_t)(y2*WW)*C_ + 4*cg;
        f32x4 cb[6];
        #pragma unroll
        for (int jj = 0; jj < 6; ++jj) {
            int col = gx0 - 1 + jj;
            cb[jj] = ((unsigned)col < WW) ? *(const f32x4*)(rp + (size_t)col*C_)
                                          : (f32x4){0.f,0.f,0.f,0.f};
        }
        #pragma unroll
        for (int j = 0; j < 4; ++j)
            accl[j] += cb[j]*wt0 + cb[j+1]*wt1 + cb[j+2]*wt2;
    }
    __syncthreads();   // B3: attn results fully in sOut (sWT no longer needed)
    #pragma unroll
    for (int j = 0; j < 4; ++j)
        #pragma unroll
        for (int i = 0; i < 4; ++i)
            sOut[(4*cg + i)*PADO + p0 + j] += accl[j][i];
    __syncthreads();   // B4: merge done

    // bias + coalesced store (out is [b][c][n])
    const int ch = tid >> 2, sub = tid & 3, pp0 = 16*sub;
    const float lb = lepe_b[ch];
    float* outp = out + (size_t)b*(size_t)(C_*NN) + (size_t)ch*NN + n0 + pp0;
    #pragma unroll
    for (int g = 0; g < 4; ++g) {
        float2 a0 = *(const float2*)(sOut + ch*PADO + pp0 + 4*g);
        float2 a1 = *(const float2*)(sOut + ch*PADO + pp0 + 4*g + 2);
        float4 o4 = { a0.x + lb, a0.y + lb, a1.x + lb, a1.y + lb };
        *(float4*)(outp + 4*g) = o4;
    }
}

extern "C" void kernel_launch(void* const* d_in, const int* in_sizes, int n_in,
                              void* d_out, int out_size, void* d_ws, size_t ws_size,
                              hipStream_t stream) {
    const float* x      = (const float*)d_in[0];
    // d_in[1], d_in[2] are h, w (fixed 128x128 — hardcoded)
    const float* qk_w   = (const float*)d_in[3];
    const float* qk_b   = (const float*)d_in[4];
    const float* lepe_w = (const float*)d_in[5];
    const float* lepe_b = (const float*)d_in[6];
    float* out = (float*)d_out;

    // workspace: only kv/km accumulators (68 KB), zeroed each launch
    float* g_kv = (float*)d_ws;              // 16*1024 f
    float* g_km = g_kv + 16*1024;            // 16*64 f
    hipMemsetAsync(d_ws, 0, (size_t)(16*1024 + 16*64) * sizeof(float), stream);

    hipLaunchKernelGGL(la_phase1, dim3(128, B_), dim3(256), 0, stream,
                       x, qk_w, qk_b, g_kv, g_km);
    hipLaunchKernelGGL(la_phase2, dim3(256, B_), dim3(256), 0, stream,
                       x, qk_w, qk_b, lepe_w, lepe_b, g_kv, g_km, out);
}